// Round 3
// baseline (86.420 us; speedup 1.0000x reference)
//
#include <hip/hip_runtime.h>

// out[b,h,w,o] = sum_{s1..s4} core[s1,s2,s3,s4,o] * a[s1]*b[s2]*c[s3]*d[s4]
// a = inp[b, h, w, :],   b = inp[b, h, w+1, :]
// c = inp[b, h+1, w, :], d = inp[b, h+1, w+1, :]
// input (1,128,128,128,2) fp32; core (2,2,2,2,4) fp32; out (128,127,127,4) fp32.
//
// R7 == R5 resubmitted again (two consecutive container-infra failures, no
// kernel signal; source audited for alignment/bounds/graph-capture tripwires
// and is clean). R5 design:
//     float4-per-lane loads + 2 outputs/lane via __shfl_down neighbor exchange.
//     Lane t loads the aligned float4 covering s-pairs (2t, 2t+1) per row:
//     5 x 16B loads/thread (was 18 x 8B), zero duplicate cache-line reads,
//     1 KB/wave per load instr (perfect coalescing). Pair 2t+2 (needed only
//     for the w=2t+1 output) comes from lane t+1 via 2 shfl_down per row
//     (DS pipe, no VMEM). CH=4 with 2 wave-chunks per 128-thread block keeps
//     16 waves/CU but halves wave lifetime -> better VMEM streaming.
//     Fetch = 5/4 x 16 MB = 20 MB; writes 33 MB NT.

#define NB 128
#define NH 128
#define NW 128
#define HN 127
#define WN 127
#define CH 4     // output rows per wave
#define WPB 2    // wave-chunks per block

typedef float float4v __attribute__((ext_vector_type(4)));

__global__ __launch_bounds__(128) void eps_kernel(const float* __restrict__ inp,
                                                  const float* __restrict__ core,
                                                  float* __restrict__ out) {
    __shared__ float cs[64];
    const int tid  = threadIdx.x;
    const int lane = tid & 63;
    const int wid  = tid >> 6;
    if (tid < 64) cs[tid] = core[tid];
    __syncthreads();

    const int h0 = blockIdx.x * (CH * WPB) + wid * CH;  // first output row of this wave
    const int b  = blockIdx.y;
    const int w0 = lane * 2;                            // first output column of this lane

    const float* base = inp + ((size_t)(b * NH) * NW + w0) * 2;
    const size_t rstride = (size_t)NW * 2;

    // One aligned float4 per row: s-pairs at w0 (.xy) and w0+1 (.zw).
    float4v r[CH + 1];
    #pragma unroll
    for (int k = 0; k <= CH; ++k) {
        int hr = h0 + k;
        if (hr > NH - 1) hr = NH - 1;          // clamp (last chunk only)
        r[k] = *(const float4v*)(base + (size_t)hr * rstride);
    }

    // Neighbor pair (index w0+2) per row, from lane t+1. Lane 63's result is
    // garbage but unused (its second output w=127 is out of range).
    float nx[CH + 1], ny[CH + 1];
    #pragma unroll
    for (int k = 0; k <= CH; ++k) {
        nx[k] = __shfl_down(r[k].x, 1);
        ny[k] = __shfl_down(r[k].y, 1);
    }

    #pragma unroll
    for (int k = 0; k < CH; ++k) {
        const int h = h0 + k;
        if (h >= HN) break;                    // trims last chunk (h0=124: 3 rows)

        // output (h, w0):   a=r[k].xy  b=r[k].zw   c=r[k+1].xy  d=r[k+1].zw
        // output (h, w0+1): a=r[k].zw  b=(nx,ny)k  c=r[k+1].zw  d=(nx,ny)k+1
        float ab0[4] = {r[k].x * r[k].z, r[k].x * r[k].w,
                        r[k].y * r[k].z, r[k].y * r[k].w};
        float cd0[4] = {r[k + 1].x * r[k + 1].z, r[k + 1].x * r[k + 1].w,
                        r[k + 1].y * r[k + 1].z, r[k + 1].y * r[k + 1].w};
        float ab1[4] = {r[k].z * nx[k], r[k].z * ny[k],
                        r[k].w * nx[k], r[k].w * ny[k]};
        float cd1[4] = {r[k + 1].z * nx[k + 1], r[k + 1].z * ny[k + 1],
                        r[k + 1].w * nx[k + 1], r[k + 1].w * ny[k + 1]};

        float4v acc0 = (float4v)(0.f), acc1 = (float4v)(0.f);
        #pragma unroll
        for (int i = 0; i < 4; ++i) {
            #pragma unroll
            for (int j = 0; j < 4; ++j) {
                const float* cr = &cs[(i * 4 + j) * 4];   // broadcast LDS read
                const float w0t = ab0[i] * cd0[j];
                const float w1t = ab1[i] * cd1[j];
                acc0.x += w0t * cr[0]; acc0.y += w0t * cr[1];
                acc0.z += w0t * cr[2]; acc0.w += w0t * cr[3];
                acc1.x += w1t * cr[0]; acc1.y += w1t * cr[1];
                acc1.z += w1t * cr[2]; acc1.w += w1t * cr[3];
            }
        }

        float* dst = out + ((size_t)(b * HN + h) * WN + w0) * 4;
        __builtin_nontemporal_store(acc0, (float4v*)dst);
        if (w0 + 1 < WN)
            __builtin_nontemporal_store(acc1, (float4v*)(dst + 4));
    }
}

extern "C" void kernel_launch(void* const* d_in, const int* in_sizes, int n_in,
                              void* d_out, int out_size, void* d_ws, size_t ws_size,
                              hipStream_t stream) {
    const float* inp  = (const float*)d_in[0];
    const float* core = (const float*)d_in[1];
    float* out = (float*)d_out;
    dim3 grid((HN + CH * WPB - 1) / (CH * WPB), NB);  // (16, 128)
    eps_kernel<<<grid, 128, 0, stream>>>(inp, core, out);
}

// Round 4
// 77.121 us; speedup vs baseline: 1.1206x; 1.1206x over previous
//
#include <hip/hip_runtime.h>

// out[b,h,w,o] = sum_{s1..s4} core[s1,s2,s3,s4,o] * a[s1]*b[s2]*c[s3]*d[s4]
// a = inp[b, h, w, :],   b = inp[b, h, w+1, :]
// c = inp[b, h+1, w, :], d = inp[b, h+1, w+1, :]
// input (1,128,128,128,2) fp32; core (2,2,2,2,4) fp32; out (128,127,127,4) fp32.
//
// R8: R4's dense-store layout (1 output per lane, w = tid; wave stores are
// 64 x 16B contiguous) + LDS row staging on the load side.
//   - R5's 2-outputs/lane variant regressed (86.4 vs 75.6 us): its paired
//     stores had 32B lane stride -> half-density NT store lines. Reverted.
//   - R4's load path was the inefficiency: 18 x 8B loads/thread, each rB
//     re-reading the neighbor's cache line (2x L1 requests). Now the block
//     stages its 9 rows (9 KB) via ~4.5 x 16B fully-coalesced float4 loads
//     per thread (one full row per wave-instr), then compute reads LDS as
//     ds_read2_b64 (8B lane stride = 2-way bank alias = free), reusing row
//     r+1 registers as next row's top. Stores/grid/FMA loop identical to R4.

#define NB 128
#define NH 128
#define NW 128
#define HN 127
#define WN 127
#define CH 8    // output rows per block

typedef float float4v __attribute__((ext_vector_type(4)));

__global__ __launch_bounds__(128) void eps_kernel(const float* __restrict__ inp,
                                                  const float* __restrict__ core,
                                                  float* __restrict__ out) {
    __shared__ float  cs[64];
    __shared__ float2 rows[CH + 1][NW];   // 9 rows x 128 pairs = 9216 B

    const int tid = threadIdx.x;
    if (tid < 64) cs[tid] = core[tid];

    const int h0 = blockIdx.x * CH;       // first output row of chunk
    const int b  = blockIdx.y;

    // ---- Stage rows h0 .. h0+CH (9 rows x 256 floats = 576 float4) ----
    const float* src = inp + (size_t)(b * NH) * NW * 2;
    #pragma unroll
    for (int i = 0; i < 5; ++i) {
        const int idx = tid + i * 128;          // float4 index
        if (idx < 576) {                        // i<4: always true (folds away)
            const int row = idx >> 6;           // 0..8
            const int c4  = idx & 63;           // float4 within row
            int hr = h0 + row;
            if (hr > NH - 1) hr = NH - 1;       // clamp (last chunk only)
            float4v v = *(const float4v*)(src + (size_t)hr * (NW * 2) + c4 * 4);
            *((float4v*)&rows[row][0] + c4) = v;
        }
    }
    __syncthreads();

    const int w = tid;
    if (w >= WN) return;

    // ---- Compute: registers carry row r+1 into next iteration ----
    float2 Av = rows[0][w];
    float2 Bv = rows[0][w + 1];

    #pragma unroll
    for (int r = 0; r < CH; ++r) {
        const int h = h0 + r;
        if (h >= HN) break;                     // trims last chunk (h0=120: 7 rows)

        const float2 Cv = rows[r + 1][w];
        const float2 Dv = rows[r + 1][w + 1];

        float ab[4] = {Av.x * Bv.x, Av.x * Bv.y,
                       Av.y * Bv.x, Av.y * Bv.y};
        float cd[4] = {Cv.x * Dv.x, Cv.x * Dv.y,
                       Cv.y * Dv.x, Cv.y * Dv.y};

        float4v acc = (float4v)(0.f);
        #pragma unroll
        for (int i = 0; i < 4; ++i) {
            #pragma unroll
            for (int j = 0; j < 4; ++j) {
                const float wt = ab[i] * cd[j];
                const float* cr = &cs[(i * 4 + j) * 4];   // broadcast LDS read
                acc.x += wt * cr[0];
                acc.y += wt * cr[1];
                acc.z += wt * cr[2];
                acc.w += wt * cr[3];
            }
        }

        float4v* dst = (float4v*)(out + ((size_t)(b * HN + h) * WN + w) * 4);
        __builtin_nontemporal_store(acc, dst);

        Av = Cv;
        Bv = Dv;
    }
}

extern "C" void kernel_launch(void* const* d_in, const int* in_sizes, int n_in,
                              void* d_out, int out_size, void* d_ws, size_t ws_size,
                              hipStream_t stream) {
    const float* inp  = (const float*)d_in[0];
    const float* core = (const float*)d_in[1];
    float* out = (float*)d_out;
    dim3 grid((HN + CH - 1) / CH, NB);  // (16, 128)
    eps_kernel<<<grid, 128, 0, stream>>>(inp, core, out);
}

// Round 5
// 77.115 us; speedup vs baseline: 1.1207x; 1.0001x over previous
//
#include <hip/hip_runtime.h>

// out[b,h,w,o] = sum_{s1..s4} core[s1,s2,s3,s4,o] * a[s1]*b[s2]*c[s3]*d[s4]
// a = inp[b, h, w, :],   b = inp[b, h, w+1, :]
// c = inp[b, h+1, w, :], d = inp[b, h+1, w+1, :]
// input (1,128,128,128,2) fp32; core (2,2,2,2,4) fp32; out (128,127,127,4) fp32.
//
// R9: store-path + occupancy experiment. Evidence so far: load-path overhauls
// (R5 float4+shfl, R8 LDS staging) were NEUTRAL vs R4's naive 18x8B loads;
// the only mover was store-line density (R5 half-density: +10 us). Theory:
// NT stores bypass L2 (no-allocate) so the 33 MB output must drain to HBM
// inside the timed dispatch, with misaligned partial lines (2032 B rows,
// base walks +48 mod 64) that can't merge; plain stores complete at L2
// (device coherence point, ~output-sized) and drain lazily under the next
// dispatch. Changes vs R8:
//   (a) plain stores instead of __builtin_nontemporal_store;
//   (b) CH=4 -> grid (32,128)=4096 blocks, up to 32 waves/CU (was 16),
//       doubling store-queue depth / latency hiding; fetch factor 5/4.

#define NB 128
#define NH 128
#define NW 128
#define HN 127
#define WN 127
#define CH 4    // output rows per block

typedef float float4v __attribute__((ext_vector_type(4)));

__global__ __launch_bounds__(128) void eps_kernel(const float* __restrict__ inp,
                                                  const float* __restrict__ core,
                                                  float* __restrict__ out) {
    __shared__ float  cs[64];
    __shared__ float2 rows[CH + 1][NW];   // 5 rows x 128 pairs = 5120 B

    const int tid = threadIdx.x;
    if (tid < 64) cs[tid] = core[tid];

    const int h0 = blockIdx.x * CH;       // first output row of chunk
    const int b  = blockIdx.y;

    // ---- Stage rows h0 .. h0+CH (5 rows x 256 floats = 320 float4) ----
    const float* src = inp + (size_t)(b * NH) * NW * 2;
    #pragma unroll
    for (int i = 0; i < 3; ++i) {
        const int idx = tid + i * 128;          // float4 index
        if (idx < (CH + 1) * 64) {              // i<2: always true (folds away)
            const int row = idx >> 6;           // 0..4
            const int c4  = idx & 63;           // float4 within row
            int hr = h0 + row;
            if (hr > NH - 1) hr = NH - 1;       // clamp (last chunk only)
            float4v v = *(const float4v*)(src + (size_t)hr * (NW * 2) + c4 * 4);
            *((float4v*)&rows[row][0] + c4) = v;
        }
    }
    __syncthreads();

    const int w = tid;
    if (w >= WN) return;

    // ---- Compute: registers carry row r+1 into next iteration ----
    float2 Av = rows[0][w];
    float2 Bv = rows[0][w + 1];

    #pragma unroll
    for (int r = 0; r < CH; ++r) {
        const int h = h0 + r;
        if (h >= HN) break;                     // trims last chunk (h0=124: 3 rows)

        const float2 Cv = rows[r + 1][w];
        const float2 Dv = rows[r + 1][w + 1];

        float ab[4] = {Av.x * Bv.x, Av.x * Bv.y,
                       Av.y * Bv.x, Av.y * Bv.y};
        float cd[4] = {Cv.x * Dv.x, Cv.x * Dv.y,
                       Cv.y * Dv.x, Cv.y * Dv.y};

        float4v acc = (float4v)(0.f);
        #pragma unroll
        for (int i = 0; i < 4; ++i) {
            #pragma unroll
            for (int j = 0; j < 4; ++j) {
                const float wt = ab[i] * cd[j];
                const float* cr = &cs[(i * 4 + j) * 4];   // broadcast LDS read
                acc.x += wt * cr[0];
                acc.y += wt * cr[1];
                acc.z += wt * cr[2];
                acc.w += wt * cr[3];
            }
        }

        // Plain (L2-allocating) store: completes at the coherence point,
        // HBM drain overlaps the next dispatch instead of this one.
        *(float4v*)(out + ((size_t)(b * HN + h) * WN + w) * 4) = acc;

        Av = Cv;
        Bv = Dv;
    }
}

extern "C" void kernel_launch(void* const* d_in, const int* in_sizes, int n_in,
                              void* d_out, int out_size, void* d_ws, size_t ws_size,
                              hipStream_t stream) {
    const float* inp  = (const float*)d_in[0];
    const float* core = (const float*)d_in[1];
    float* out = (float*)d_out;
    dim3 grid((HN + CH - 1) / CH, NB);  // (32, 128)
    eps_kernel<<<grid, 128, 0, stream>>>(inp, core, out);
}